// Round 1
// baseline (1548.012 us; speedup 1.0000x reference)
//
#include <hip/hip_runtime.h>

// Problem: inputs [32768,512] f32, codebook [8192,512] f32
// out[n,k] = softmax_k( 2*x_n.c_k - ||c_k||^2 )   (x_sqr cancels in softmax)
//
// Pipeline:
//  1. split X -> X_hi/X_lo bf16, split C -> C_hi/C_lo bf16 (in ws)
//  2. cb_sqr[k] = sum_d C[k][d]^2
//  3. GEMM (3-product bf16 split, 16x16x32 MFMA, 128x128 tiles) -> logits in d_out
//     + per-(row, colblock) softmax partials (max, sumexp) in ws
//  4. combine partials -> row max m, row inv-sum
//  5. normalize d_out in place: exp(logit-m)*inv_sum

typedef __attribute__((ext_vector_type(8))) __bf16 bf16x8;
typedef __attribute__((ext_vector_type(4))) float f32x4;

typedef __attribute__((address_space(1))) const void global_cvoid;
typedef __attribute__((address_space(3))) void lds_void;

__device__ inline unsigned short f32_to_bf16_rne(float f) {
    unsigned int u = __float_as_uint(f);
    unsigned int r = u + 0x7FFFu + ((u >> 16) & 1u);
    return (unsigned short)(r >> 16);
}
__device__ inline float bf16u_to_f32(unsigned short h) {
    return __uint_as_float(((unsigned int)h) << 16);
}

// ---------------- prep: fp32 -> bf16 hi/lo split ----------------
__global__ void split_kernel(const float* __restrict__ in,
                             unsigned short* __restrict__ hi,
                             unsigned short* __restrict__ lo, int n4) {
    int i = blockIdx.x * blockDim.x + threadIdx.x;
    int stride = gridDim.x * blockDim.x;
    for (; i < n4; i += stride) {
        float4 v = reinterpret_cast<const float4*>(in)[i];
        float vv[4] = {v.x, v.y, v.z, v.w};
        ushort4 hv, lv;
        unsigned short h[4], l[4];
#pragma unroll
        for (int j = 0; j < 4; ++j) {
            h[j] = f32_to_bf16_rne(vv[j]);
            float r = vv[j] - bf16u_to_f32(h[j]);
            l[j] = f32_to_bf16_rne(r);
        }
        hv.x = h[0]; hv.y = h[1]; hv.z = h[2]; hv.w = h[3];
        lv.x = l[0]; lv.y = l[1]; lv.z = l[2]; lv.w = l[3];
        reinterpret_cast<ushort4*>(hi)[i] = hv;
        reinterpret_cast<ushort4*>(lo)[i] = lv;
    }
}

// ---------------- prep: codebook row squared norms ----------------
__global__ void rowsq_kernel(const float* __restrict__ cb, float* __restrict__ out) {
    int row = blockIdx.x * 4 + (threadIdx.x >> 6);
    int lane = threadIdx.x & 63;
    const float4* p = reinterpret_cast<const float4*>(cb + (size_t)row * 512);
    float4 a = p[lane];
    float4 b = p[lane + 64];
    float s = a.x * a.x + a.y * a.y + a.z * a.z + a.w * a.w +
              b.x * b.x + b.y * b.y + b.z * b.z + b.w * b.w;
#pragma unroll
    for (int o = 32; o >= 1; o >>= 1) s += __shfl_xor(s, o);
    if (lane == 0) out[row] = s;
}

// ---------------- GEMM: logits + per-tile softmax partials ----------------
// Grid: 16384 blocks (tm = bid>>6 in [0,256), tn = bid&63 in [0,64))
// Block: 256 threads = 4 waves (2x2), each wave owns a 64x64 output subtile.
__global__ __launch_bounds__(256) void gemm_kernel(
    const unsigned short* __restrict__ Ah, const unsigned short* __restrict__ Al,
    const unsigned short* __restrict__ Bh, const unsigned short* __restrict__ Bl,
    const float* __restrict__ cbq, float* __restrict__ out,
    float* __restrict__ max_part, float* __restrict__ sum_part) {
    __shared__ unsigned short smem[4 * 4096];  // Ah,Al,Bh,Bl tiles: 128x32 bf16 each
    __shared__ float sred_max[2][128];
    __shared__ float sred_sum[2][128];

    const int t = threadIdx.x;
    const int lane = t & 63;
    const int w = t >> 6;
    const int wm = w >> 1, wn = w & 1;
    const int fr = lane & 15, fg = lane >> 4;
    const int bid = blockIdx.x;
    const int tm = bid >> 6, tn = bid & 63;
    const int row0 = tm * 128, col0 = tn * 128;

    f32x4 acc[4][4] = {};

    // staging geometry: thread t loads 16B: row = r*64 + (t>>2), k-elem offset (t&3)*8
    const int s_lrow = t >> 2;
    const int s_kb = (t & 3) * 8;
    const unsigned short* const srcs[4] = {
        Ah + (size_t)row0 * 512, Al + (size_t)row0 * 512,
        Bh + (size_t)col0 * 512, Bl + (size_t)col0 * 512};

    for (int kt = 0; kt < 512; kt += 32) {
#pragma unroll
        for (int tile = 0; tile < 4; ++tile) {
            const unsigned short* base = srcs[tile] + kt + s_kb;
#pragma unroll
            for (int r = 0; r < 2; ++r) {
                const unsigned short* g = base + (size_t)(s_lrow + r * 64) * 512;
                unsigned short* l = smem + tile * 4096 + r * 2048 + w * 512;  // wave-uniform base
                __builtin_amdgcn_global_load_lds((global_cvoid*)g, (lds_void*)l, 16, 0, 0);
            }
        }
        __syncthreads();

        bf16x8 ah[4], al[4], bh[4], bl[4];
#pragma unroll
        for (int m = 0; m < 4; ++m) {
            int ro = (wm * 64 + m * 16 + fr) * 32 + fg * 8;
            ah[m] = *reinterpret_cast<const bf16x8*>(smem + ro);
            al[m] = *reinterpret_cast<const bf16x8*>(smem + 4096 + ro);
        }
#pragma unroll
        for (int n = 0; n < 4; ++n) {
            int co = (wn * 64 + n * 16 + fr) * 32 + fg * 8;
            bh[n] = *reinterpret_cast<const bf16x8*>(smem + 2 * 4096 + co);
            bl[n] = *reinterpret_cast<const bf16x8*>(smem + 3 * 4096 + co);
        }
#pragma unroll
        for (int m = 0; m < 4; ++m)
#pragma unroll
            for (int n = 0; n < 4; ++n) {
                acc[m][n] = __builtin_amdgcn_mfma_f32_16x16x32_bf16(ah[m], bh[n], acc[m][n], 0, 0, 0);
                acc[m][n] = __builtin_amdgcn_mfma_f32_16x16x32_bf16(ah[m], bl[n], acc[m][n], 0, 0, 0);
                acc[m][n] = __builtin_amdgcn_mfma_f32_16x16x32_bf16(al[m], bh[n], acc[m][n], 0, 0, 0);
            }
        __syncthreads();
    }

    // ---- epilogue: logits, per-tile row max + sumexp, stores ----
    float cq[4];
#pragma unroll
    for (int n = 0; n < 4; ++n) cq[n] = cbq[col0 + wn * 64 + n * 16 + fr];

#pragma unroll
    for (int m = 0; m < 4; ++m)
#pragma unroll
        for (int n = 0; n < 4; ++n)
#pragma unroll
            for (int r = 0; r < 4; ++r)
                acc[m][n][r] = 2.0f * acc[m][n][r] - cq[n];

    // per-row max over this wave's 64 cols (reduce over n frags + 16 col-lanes)
    float rmx[4][4];
#pragma unroll
    for (int m = 0; m < 4; ++m)
#pragma unroll
        for (int r = 0; r < 4; ++r) {
            float v = acc[m][0][r];
#pragma unroll
            for (int n = 1; n < 4; ++n) v = fmaxf(v, acc[m][n][r]);
#pragma unroll
            for (int o = 1; o < 16; o <<= 1) v = fmaxf(v, __shfl_xor(v, o));
            rmx[m][r] = v;
        }
    if (fr == 0) {
#pragma unroll
        for (int m = 0; m < 4; ++m)
#pragma unroll
            for (int r = 0; r < 4; ++r)
                sred_max[wn][wm * 64 + m * 16 + fg * 4 + r] = rmx[m][r];
    }
    __syncthreads();
#pragma unroll
    for (int m = 0; m < 4; ++m)
#pragma unroll
        for (int r = 0; r < 4; ++r) {
            int rl = wm * 64 + m * 16 + fg * 4 + r;
            rmx[m][r] = fmaxf(sred_max[0][rl], sred_max[1][rl]);
        }
    // per-row sum of exp(logit - rowmax_tile)
    float rsm[4][4];
#pragma unroll
    for (int m = 0; m < 4; ++m)
#pragma unroll
        for (int r = 0; r < 4; ++r) {
            float s = 0.0f;
#pragma unroll
            for (int n = 0; n < 4; ++n) s += __expf(acc[m][n][r] - rmx[m][r]);
#pragma unroll
            for (int o = 1; o < 16; o <<= 1) s += __shfl_xor(s, o);
            rsm[m][r] = s;
        }
    if (fr == 0) {
#pragma unroll
        for (int m = 0; m < 4; ++m)
#pragma unroll
            for (int r = 0; r < 4; ++r)
                sred_sum[wn][wm * 64 + m * 16 + fg * 4 + r] = rsm[m][r];
    }
    __syncthreads();
    if (wn == 0 && fr == 0) {
#pragma unroll
        for (int m = 0; m < 4; ++m)
#pragma unroll
            for (int r = 0; r < 4; ++r) {
                int rl = wm * 64 + m * 16 + fg * 4 + r;
                size_t grow = (size_t)(row0 + rl);
                max_part[grow * 64 + tn] = rmx[m][r];
                sum_part[grow * 64 + tn] = sred_sum[0][rl] + sred_sum[1][rl];
            }
    }
    // store raw logits
#pragma unroll
    for (int m = 0; m < 4; ++m)
#pragma unroll
        for (int n = 0; n < 4; ++n)
#pragma unroll
            for (int r = 0; r < 4; ++r) {
                size_t grow = (size_t)(row0 + wm * 64 + m * 16 + fg * 4 + r);
                int gcol = col0 + wn * 64 + n * 16 + fr;
                out[grow * 8192 + gcol] = acc[m][n][r];
            }
}

// ---------------- combine partials over 64 col-blocks per row ----------------
__global__ void combine_kernel(const float* __restrict__ max_part,
                               const float* __restrict__ sum_part,
                               float* __restrict__ row_m, float* __restrict__ row_is) {
    int row = blockIdx.x * 4 + (threadIdx.x >> 6);
    int lane = threadIdx.x & 63;
    size_t off = (size_t)row * 64 + lane;
    float m = max_part[off];
    float s = sum_part[off];
    float gm = m;
#pragma unroll
    for (int o = 32; o >= 1; o >>= 1) gm = fmaxf(gm, __shfl_xor(gm, o));
    float c = s * __expf(m - gm);
#pragma unroll
    for (int o = 32; o >= 1; o >>= 1) c += __shfl_xor(c, o);
    if (lane == 0) {
        row_m[row] = gm;
        row_is[row] = 1.0f / c;
    }
}

// ---------------- normalize in place ----------------
__global__ void norm_kernel(float* __restrict__ out, const float* __restrict__ row_m,
                            const float* __restrict__ row_is) {
    size_t i = (size_t)blockIdx.x * blockDim.x + threadIdx.x;
    size_t stride = (size_t)gridDim.x * blockDim.x;
    const size_t n4 = 268435456ull / 4;  // 32768*8192/4
    float4* p = reinterpret_cast<float4*>(out);
    for (; i < n4; i += stride) {
        int row = (int)(i >> 11);  // 8192/4 = 2048 float4 per row
        float m = row_m[row];
        float is = row_is[row];
        float4 v = p[i];
        v.x = __expf(v.x - m) * is;
        v.y = __expf(v.y - m) * is;
        v.z = __expf(v.z - m) * is;
        v.w = __expf(v.w - m) * is;
        p[i] = v;
    }
}

extern "C" void kernel_launch(void* const* d_in, const int* in_sizes, int n_in,
                              void* d_out, int out_size, void* d_ws, size_t ws_size,
                              hipStream_t stream) {
    const float* x = (const float*)d_in[0];   // [32768,512]
    const float* cb = (const float*)d_in[1];  // [8192,512]
    float* out = (float*)d_out;               // [32768,8192]
    char* ws = (char*)d_ws;

    // ws layout (bytes)
    unsigned short* Xh = (unsigned short*)(ws);                 // 33,554,432
    unsigned short* Xl = (unsigned short*)(ws + 33554432ull);   // 33,554,432
    unsigned short* Ch = (unsigned short*)(ws + 67108864ull);   // 8,388,608
    unsigned short* Cl = (unsigned short*)(ws + 75497472ull);   // 8,388,608
    float* cbq       = (float*)(ws + 83886080ull);              // 32,768
    float* max_part  = (float*)(ws + 83918848ull);              // 8,388,608
    float* sum_part  = (float*)(ws + 92307456ull);              // 8,388,608
    float* row_m     = (float*)(ws + 100696064ull);             // 131,072
    float* row_is    = (float*)(ws + 100827136ull);             // 131,072  -> total 100,958,208 B

    split_kernel<<<2048, 256, 0, stream>>>(x, Xh, Xl, 32768 * 512 / 4);
    split_kernel<<<1024, 256, 0, stream>>>(cb, Ch, Cl, 8192 * 512 / 4);
    rowsq_kernel<<<2048, 256, 0, stream>>>(cb, cbq);
    gemm_kernel<<<16384, 256, 0, stream>>>(Xh, Xl, Ch, Cl, cbq, out, max_part, sum_part);
    combine_kernel<<<8192, 256, 0, stream>>>(max_part, sum_part, row_m, row_is);
    norm_kernel<<<4096, 256, 0, stream>>>(out, row_m, row_is);
}